// Round 3
// baseline (345.762 us; speedup 1.0000x reference)
//
#include <hip/hip_runtime.h>

// WarpLayer: bilinear backward warp.
// image [B,H,W,C] f32, flow [B,H,W,2] f32 -> out [B,H,W,C] f32
// q = grid - flow; y0 = clip(floor(qy),0,H-2); alpha = clip(q - floor_clipped, 0, 1)
// out = lerp over 4 corners.
//
// Diagnosis (R1/R2 counters): latency-bound gather. VALUBusy 8%, HBM 33%,
// occupancy 80% -- waves spend ~90% of life stalled on vmcnt with only 4KB
// outstanding each. Fix: 2 pixels per thread so each wave carries 8KB of
// gather loads issued back-to-back before first use (double MLP).
//
// Layout: C=32 innermost => each corner pixel = 128 contiguous bytes,
// 128B-aligned. 8 threads per pixel (one float4 channel-group each); a wave
// covers 16 pixels (2 per lane, 32 apart in the same row). Block of 256
// threads = 64 consecutive pixels, row-aligned (64 | 512).
//
// Plain stores (NT stores regressed ~10-15us in R1/R2: bypassing L2 write-
// combining contends with the latency-critical gathers).
//
// XCD swizzle: each XCD owns a contiguous 1/8 pixel slab (= one batch image)
// so its ~sliding gather window stays in its private 4MB L2.

typedef float f4 __attribute__((ext_vector_type(4)));

#define WB 8
#define WH 384
#define WW 512
#define WC 32
#define NPIX (WB * WH * WW)       // 1,572,864
#define NBLK (NPIX / 64)          // 24,576 blocks (64 pixels per block)
#define BPX  (NBLK / 8)           // 3,072 blocks per XCD slab

__global__ __launch_bounds__(256) void warp_kernel(
    const float* __restrict__ image,
    const float* __restrict__ flow,
    float* __restrict__ out)
{
    // Bijective XCD swizzle (round-robin dispatch: bid%8 -> XCD).
    const int bsw = (blockIdx.x & 7) * BPX + (blockIdx.x >> 3);
    const int t   = threadIdx.x;
    const int cg  = t & 7;         // float4 channel-group within the pixel
    const int lp  = t >> 3;        // 0..31
    const int p0  = bsw * 64 + lp; // pixel 0
    const int p1  = p0 + 32;       // pixel 1 (same row: w0 <= 479, w1 = w0+32)

    // Both pixels share b,h.
    const int w0 = p0 & (WW - 1);
    const int bh = p0 >> 9;
    const int h  = bh % WH;
    const int b  = bh / WH;
    const int w1 = w0 + 32;

    // flow[..,0] = dy, flow[..,1] = dx ; q = grid - flow
    const float2 f0 = ((const float2*)flow)[p0];
    const float2 f1 = ((const float2*)flow)[p1];

    const float qy0 = (float)h  - f0.x;
    const float qx0 = (float)w0 - f0.y;
    const float qy1 = (float)h  - f1.x;
    const float qx1 = (float)w1 - f1.y;

    const float fly0 = fminf(fmaxf(floorf(qy0), 0.0f), (float)(WH - 2));
    const float flx0 = fminf(fmaxf(floorf(qx0), 0.0f), (float)(WW - 2));
    const float fly1 = fminf(fmaxf(floorf(qy1), 0.0f), (float)(WH - 2));
    const float flx1 = fminf(fmaxf(floorf(qx1), 0.0f), (float)(WW - 2));
    const int y0a = (int)fly0, x0a = (int)flx0;
    const int y0b = (int)fly1, x0b = (int)flx1;
    const float ay0 = fminf(fmaxf(qy0 - fly0, 0.0f), 1.0f);
    const float ax0 = fminf(fmaxf(qx0 - flx0, 0.0f), 1.0f);
    const float ay1 = fminf(fmaxf(qy1 - fly1, 0.0f), 1.0f);
    const float ax1 = fminf(fmaxf(qx1 - flx1, 0.0f), 1.0f);

    // float4-unit indices: pixel p has 8 float4 groups; 32-bit (max ~12.6M).
    const f4* __restrict__ img4 = (const f4*)image;
    const int baseA = ((b * WH + y0a) * WW + x0a) * 8 + cg;
    const int baseB = ((b * WH + y0b) * WW + x0b) * 8 + cg;

    // Issue all 8 gathers before any use (MLP).
    const f4 tlA = img4[baseA];
    const f4 trA = img4[baseA + 8];
    const f4 blA = img4[baseA + WW * 8];
    const f4 brA = img4[baseA + WW * 8 + 8];
    const f4 tlB = img4[baseB];
    const f4 trB = img4[baseB + 8];
    const f4 blB = img4[baseB + WW * 8];
    const f4 brB = img4[baseB + WW * 8 + 8];

    const f4 topA = tlA + ax0 * (trA - tlA);
    const f4 botA = blA + ax0 * (brA - blA);
    const f4 rA   = topA + ay0 * (botA - topA);
    const f4 topB = tlB + ax1 * (trB - tlB);
    const f4 botB = blB + ax1 * (brB - blB);
    const f4 rB   = topB + ay1 * (botB - topB);

    f4* out4 = (f4*)out;
    out4[p0 * 8 + cg] = rA;
    out4[p1 * 8 + cg] = rB;
}

extern "C" void kernel_launch(void* const* d_in, const int* in_sizes, int n_in,
                              void* d_out, int out_size, void* d_ws, size_t ws_size,
                              hipStream_t stream)
{
    const float* image = (const float*)d_in[0];
    const float* flow  = (const float*)d_in[1];
    float* out = (float*)d_out;

    warp_kernel<<<NBLK, 256, 0, stream>>>(image, flow, out);
}